// Round 1
// baseline (368.066 us; speedup 1.0000x reference)
//
#include <hip/hip_runtime.h>
#include <stdint.h>

#define IN_D  4096
#define OUT_D 4096
#define BATCH 4096
#define NEG_SLOPE 0.1f

typedef __attribute__((ext_vector_type(8))) short short8;
typedef __attribute__((ext_vector_type(4))) float f32x4;

// ---------- helpers ----------
__device__ __forceinline__ unsigned short f2bf(float f) {
    // round-to-nearest-even bf16
    unsigned u = __builtin_bit_cast(unsigned, f);
    u += 0x7FFFu + ((u >> 16) & 1u);
    return (unsigned short)(u >> 16);
}

// ---------- ws zero (tag + Wt regions) ----------
__global__ void zero_kernel(uint4* __restrict__ p, int n4) {
    int stride = gridDim.x * blockDim.x;
    uint4 z = make_uint4(0u, 0u, 0u, 0u);
    for (int i = blockIdx.x * blockDim.x + threadIdx.x; i < n4; i += stride) p[i] = z;
}

// ---------- x fp32 -> bf16 ----------
__global__ void cvt_kernel(const float4* __restrict__ x, ushort4* __restrict__ xb, int n4) {
    int stride = gridDim.x * blockDim.x;
    for (int i = blockIdx.x * blockDim.x + threadIdx.x; i < n4; i += stride) {
        float4 v = x[i];
        ushort4 o;
        o.x = f2bf(v.x); o.y = f2bf(v.y); o.z = f2bf(v.z); o.w = f2bf(v.w);
        xb[i] = o;
    }
}

// ---------- scatter pass 1: last-write-wins tag (max nnz index wins) ----------
__global__ void tag_kernel(const int* __restrict__ rows, const int* __restrict__ cols,
                           unsigned* __restrict__ tag, int nnz) {
    int i = blockIdx.x * blockDim.x + threadIdx.x;
    if (i < nnz) {
        size_t loc = (size_t)cols[i] * IN_D + rows[i];   // Wt[col][row]
        atomicMax(&tag[loc], (unsigned)(i + 1));
    }
}

// ---------- scatter pass 2: winner writes bf16 weight ----------
__global__ void scat_kernel(const int* __restrict__ rows, const int* __restrict__ cols,
                            const float* __restrict__ w, const unsigned* __restrict__ tag,
                            unsigned short* __restrict__ Wt, int nnz) {
    int i = blockIdx.x * blockDim.x + threadIdx.x;
    if (i < nnz) {
        size_t loc = (size_t)cols[i] * IN_D + rows[i];
        if (tag[loc] == (unsigned)(i + 1)) Wt[loc] = f2bf(w[i]);
    }
}

// ---------- GEMM: out = leaky_relu(bias + Xb @ Wt^T), 128x128 tile, bf16 MFMA ----------
#define BM 128
#define BN 128
#define BK 32
#define LDT 40   // padded LDS row stride in bf16 elems (80 B = 5*16 B, 2-way bank alias only)

__global__ __launch_bounds__(256) void gemm_kernel(
        const unsigned short* __restrict__ Xb,   // [BATCH][IN_D] bf16
        const unsigned short* __restrict__ Wt,   // [OUT_D][IN_D] bf16 (transposed dense W)
        const float* __restrict__ bias,          // [OUT_D]
        float* __restrict__ out)                 // [BATCH][OUT_D] fp32
{
    __shared__ unsigned short As[BM * LDT];
    __shared__ unsigned short Bs[BN * LDT];

    const int tid  = threadIdx.x;
    const int lane = tid & 63;
    const int wave = tid >> 6;
    const int wm = (wave >> 1) * 64;   // wave row offset in tile
    const int wn = (wave & 1) * 64;    // wave col offset in tile
    const int m0 = blockIdx.y * BM;
    const int n0 = blockIdx.x * BN;

    const int lr = lane & 15;          // fragment row/col
    const int kg = lane >> 4;          // k-group 0..3

    f32x4 acc[4][4] = {};

    for (int k0 = 0; k0 < IN_D; k0 += BK) {
        __syncthreads();   // previous iteration's fragment reads done
        // stage A and B tiles: 512 16B-loads each side, 2 per thread
        #pragma unroll
        for (int s = 0; s < 2; ++s) {
            int q   = tid + s * 256;
            int row = q >> 2;            // 0..127
            int kc  = (q & 3) * 8;       // 0,8,16,24
            uint4 va = *(const uint4*)(&Xb[(size_t)(m0 + row) * IN_D + k0 + kc]);
            *(uint4*)(&As[row * LDT + kc]) = va;
            uint4 vb = *(const uint4*)(&Wt[(size_t)(n0 + row) * IN_D + k0 + kc]);
            *(uint4*)(&Bs[row * LDT + kc]) = vb;
        }
        __syncthreads();

        short8 a[4], b[4];
        #pragma unroll
        for (int mi = 0; mi < 4; ++mi)
            a[mi] = *(const short8*)(&As[(wm + mi * 16 + lr) * LDT + kg * 8]);
        #pragma unroll
        for (int ni = 0; ni < 4; ++ni)
            b[ni] = *(const short8*)(&Bs[(wn + ni * 16 + lr) * LDT + kg * 8]);

        #pragma unroll
        for (int mi = 0; mi < 4; ++mi)
            #pragma unroll
            for (int ni = 0; ni < 4; ++ni)
                acc[mi][ni] = __builtin_amdgcn_mfma_f32_16x16x32_bf16(
                                  a[mi], b[ni], acc[mi][ni], 0, 0, 0);
    }

    // epilogue: bias + leaky_relu, fp32 store
    float bfrag[4];
    #pragma unroll
    for (int ni = 0; ni < 4; ++ni) bfrag[ni] = bias[n0 + wn + ni * 16 + lr];

    #pragma unroll
    for (int mi = 0; mi < 4; ++mi) {
        #pragma unroll
        for (int ni = 0; ni < 4; ++ni) {
            const int col = n0 + wn + ni * 16 + lr;
            #pragma unroll
            for (int r = 0; r < 4; ++r) {
                const int row = m0 + wm + mi * 16 + kg * 4 + r;
                float v = acc[mi][ni][r] + bfrag[ni];
                v = v > 0.0f ? v : v * NEG_SLOPE;
                out[(size_t)row * OUT_D + col] = v;
            }
        }
    }
}

// ---------- launch ----------
extern "C" void kernel_launch(void* const* d_in, const int* in_sizes, int n_in,
                              void* d_out, int out_size, void* d_ws, size_t ws_size,
                              hipStream_t stream) {
    const float* x    = (const float*)d_in[0];
    const float* w    = (const float*)d_in[1];
    const float* bias = (const float*)d_in[2];
    const int*   rows = (const int*)d_in[3];
    const int*   cols = (const int*)d_in[4];
    const int nnz = in_sizes[1];
    float* out = (float*)d_out;

    // ws layout: tag u32[16.7M] | Wt bf16[16.7M] | Xb bf16[16.7M]  = 128 MiB
    const size_t NW = (size_t)IN_D * OUT_D;
    unsigned*        tag = (unsigned*)d_ws;
    unsigned short*  Wt  = (unsigned short*)((char*)d_ws + NW * 4);
    unsigned short*  Xb  = (unsigned short*)((char*)d_ws + NW * 4 + NW * 2);

    // zero tag + Wt (96 MiB -> 6291456 uint4)
    zero_kernel<<<2048, 256, 0, stream>>>((uint4*)d_ws, (int)((NW * 6) / 16));
    // convert x to bf16 (16.7M floats -> 4194304 float4)
    cvt_kernel<<<2048, 256, 0, stream>>>((const float4*)x, (ushort4*)Xb,
                                         (int)((size_t)BATCH * IN_D / 4));
    // deterministic last-write-wins scatter
    tag_kernel<<<(nnz + 255) / 256, 256, 0, stream>>>(rows, cols, tag, nnz);
    scat_kernel<<<(nnz + 255) / 256, 256, 0, stream>>>(rows, cols, w, tag, Wt, nnz);

    dim3 grid(OUT_D / BN, BATCH / BM);
    gemm_kernel<<<grid, 256, 0, stream>>>(Xb, Wt, bias, out);
}

// Round 2
// 344.762 us; speedup vs baseline: 1.0676x; 1.0676x over previous
//
#include <hip/hip_runtime.h>
#include <stdint.h>

#define IN_D  4096
#define OUT_D 4096
#define BATCH 4096
#define NEG_SLOPE 0.1f

typedef __attribute__((ext_vector_type(8))) short short8;
typedef __attribute__((ext_vector_type(4))) float f32x4;

// ---------- helpers ----------
__device__ __forceinline__ unsigned short f2bf(float f) {
    unsigned u = __builtin_bit_cast(unsigned, f);
    u += 0x7FFFu + ((u >> 16) & 1u);
    return (unsigned short)(u >> 16);
}

// async global->LDS, 16 bytes per lane. LDS dest must be wave-uniform base
// (builtin adds lane*16 itself); global src is per-lane.
__device__ __forceinline__ void gload_lds16(const unsigned short* gsrc, unsigned short* lds) {
    __builtin_amdgcn_global_load_lds(
        (const __attribute__((address_space(1))) unsigned int*)gsrc,
        (__attribute__((address_space(3))) unsigned int*)lds,
        16, 0, 0);
}

// ---------- ws zero (tag + Wt regions) ----------
__global__ void zero_kernel(uint4* __restrict__ p, int n4) {
    int stride = gridDim.x * blockDim.x;
    uint4 z = make_uint4(0u, 0u, 0u, 0u);
    for (int i = blockIdx.x * blockDim.x + threadIdx.x; i < n4; i += stride) p[i] = z;
}

// ---------- x fp32 -> bf16 ----------
__global__ void cvt_kernel(const float4* __restrict__ x, ushort4* __restrict__ xb, int n4) {
    int stride = gridDim.x * blockDim.x;
    for (int i = blockIdx.x * blockDim.x + threadIdx.x; i < n4; i += stride) {
        float4 v = x[i];
        ushort4 o;
        o.x = f2bf(v.x); o.y = f2bf(v.y); o.z = f2bf(v.z); o.w = f2bf(v.w);
        xb[i] = o;
    }
}

// ---------- scatter pass 1: last-write-wins tag (max nnz index wins) ----------
__global__ void tag_kernel(const int* __restrict__ rows, const int* __restrict__ cols,
                           unsigned* __restrict__ tag, int nnz) {
    int i = blockIdx.x * blockDim.x + threadIdx.x;
    if (i < nnz) {
        size_t loc = (size_t)cols[i] * IN_D + rows[i];   // Wt[col][row]
        atomicMax(&tag[loc], (unsigned)(i + 1));
    }
}

// ---------- scatter pass 2: winner writes bf16 weight ----------
__global__ void scat_kernel(const int* __restrict__ rows, const int* __restrict__ cols,
                            const float* __restrict__ w, const unsigned* __restrict__ tag,
                            unsigned short* __restrict__ Wt, int nnz) {
    int i = blockIdx.x * blockDim.x + threadIdx.x;
    if (i < nnz) {
        size_t loc = (size_t)cols[i] * IN_D + rows[i];
        if (tag[loc] == (unsigned)(i + 1)) Wt[loc] = f2bf(w[i]);
    }
}

// ---------- GEMM: out = leaky_relu(bias + Xb @ Wt^T) ----------
// m97 structure: 128x128 tile, BK=32, linear LDS [128][32], global_load_lds x16
#define BM 128
#define BN 128
#define BK 32

__global__ __launch_bounds__(256) void gemm_kernel(
        const unsigned short* __restrict__ Xb,   // [BATCH][IN_D] bf16
        const unsigned short* __restrict__ Wt,   // [OUT_D][IN_D] bf16
        const float* __restrict__ bias,          // [OUT_D]
        float* __restrict__ out)                 // [BATCH][OUT_D] fp32
{
    __shared__ unsigned short As[BM * BK];   // linear: row*32 + k  (64B rows)
    __shared__ unsigned short Bs[BN * BK];

    const int tid  = threadIdx.x;
    const int lane = tid & 63;
    const int wave = tid >> 6;
    const int wm = (wave >> 1) * 64;
    const int wn = (wave & 1) * 64;
    const int m0 = blockIdx.y * BM;
    const int n0 = blockIdx.x * BN;

    const int lr = lane & 15;
    const int kg = lane >> 4;

    // staging geometry: each wave stages 2 chunks of 16 rows per side.
    // lane l -> row_in_chunk = l>>2, 16B col = (l&3)*16  (i.e. k elem (l&3)*8)
    const int srow = wave * 32;                  // wave's first staging row
    const int lrow = lane >> 2;                  // 0..15
    const int lkel = (lane & 3) * 8;             // k element offset of this lane's 16B

    f32x4 acc[4][4] = {};

    for (int k0 = 0; k0 < IN_D; k0 += BK) {
        __syncthreads();   // fragment reads of previous iter done
        #pragma unroll
        for (int s = 0; s < 2; ++s) {
            const int r = srow + s * 16;         // chunk base row (wave-uniform)
            gload_lds16(&Xb[(size_t)(m0 + r + lrow) * IN_D + k0 + lkel], &As[r * BK]);
            gload_lds16(&Wt[(size_t)(n0 + r + lrow) * IN_D + k0 + lkel], &Bs[r * BK]);
        }
        __syncthreads();   // implies s_waitcnt vmcnt(0): LDS tiles ready

        short8 a[4], b[4];
        #pragma unroll
        for (int mi = 0; mi < 4; ++mi)
            a[mi] = *(const short8*)(&As[(wm + mi * 16 + lr) * BK + kg * 8]);
        #pragma unroll
        for (int ni = 0; ni < 4; ++ni)
            b[ni] = *(const short8*)(&Bs[(wn + ni * 16 + lr) * BK + kg * 8]);

        #pragma unroll
        for (int mi = 0; mi < 4; ++mi)
            #pragma unroll
            for (int ni = 0; ni < 4; ++ni)
                acc[mi][ni] = __builtin_amdgcn_mfma_f32_16x16x32_bf16(
                                  a[mi], b[ni], acc[mi][ni], 0, 0, 0);
    }

    float bfrag[4];
    #pragma unroll
    for (int ni = 0; ni < 4; ++ni) bfrag[ni] = bias[n0 + wn + ni * 16 + lr];

    #pragma unroll
    for (int mi = 0; mi < 4; ++mi) {
        #pragma unroll
        for (int ni = 0; ni < 4; ++ni) {
            const int col = n0 + wn + ni * 16 + lr;
            #pragma unroll
            for (int r = 0; r < 4; ++r) {
                const int row = m0 + wm + mi * 16 + kg * 4 + r;
                float v = acc[mi][ni][r] + bfrag[ni];
                v = v > 0.0f ? v : v * NEG_SLOPE;
                out[(size_t)row * OUT_D + col] = v;
            }
        }
    }
}

// ---------- launch ----------
extern "C" void kernel_launch(void* const* d_in, const int* in_sizes, int n_in,
                              void* d_out, int out_size, void* d_ws, size_t ws_size,
                              hipStream_t stream) {
    const float* x    = (const float*)d_in[0];
    const float* w    = (const float*)d_in[1];
    const float* bias = (const float*)d_in[2];
    const int*   rows = (const int*)d_in[3];
    const int*   cols = (const int*)d_in[4];
    const int nnz = in_sizes[1];
    float* out = (float*)d_out;

    const size_t NW = (size_t)IN_D * OUT_D;
    unsigned*        tag = (unsigned*)d_ws;
    unsigned short*  Wt  = (unsigned short*)((char*)d_ws + NW * 4);
    unsigned short*  Xb  = (unsigned short*)((char*)d_ws + NW * 4 + NW * 2);

    zero_kernel<<<2048, 256, 0, stream>>>((uint4*)d_ws, (int)((NW * 6) / 16));
    cvt_kernel<<<2048, 256, 0, stream>>>((const float4*)x, (ushort4*)Xb,
                                         (int)((size_t)BATCH * IN_D / 4));
    tag_kernel<<<(nnz + 255) / 256, 256, 0, stream>>>(rows, cols, tag, nnz);
    scat_kernel<<<(nnz + 255) / 256, 256, 0, stream>>>(rows, cols, w, tag, Wt, nnz);

    dim3 grid(OUT_D / BN, BATCH / BM);
    gemm_kernel<<<grid, 256, 0, stream>>>(Xb, Wt, bias, out);
}

// Round 3
// 275.995 us; speedup vs baseline: 1.3336x; 1.2492x over previous
//
#include <hip/hip_runtime.h>
#include <stdint.h>

#define IN_D  4096
#define OUT_D 4096
#define BATCH 4096
#define NEG_SLOPE 0.1f

typedef __attribute__((ext_vector_type(8))) short short8;
typedef __attribute__((ext_vector_type(4))) float f32x4;

// ---------- helpers ----------
__device__ __forceinline__ unsigned short f2bf(float f) {
    unsigned u = __builtin_bit_cast(unsigned, f);
    u += 0x7FFFu + ((u >> 16) & 1u);
    return (unsigned short)(u >> 16);
}

__device__ __forceinline__ void gload_lds16(const unsigned short* gsrc, unsigned short* ldsp) {
    __builtin_amdgcn_global_load_lds(
        (const __attribute__((address_space(1))) unsigned int*)gsrc,
        (__attribute__((address_space(3))) unsigned int*)ldsp,
        16, 0, 0);
}

// ---------- ws zero ----------
__global__ void zero_kernel(uint4* __restrict__ p, int n4) {
    int stride = gridDim.x * blockDim.x;
    uint4 z = make_uint4(0u, 0u, 0u, 0u);
    for (int i = blockIdx.x * blockDim.x + threadIdx.x; i < n4; i += stride) p[i] = z;
}

// ---------- x fp32 -> bf16 ----------
__global__ void cvt_kernel(const float4* __restrict__ x, ushort4* __restrict__ xb, int n4) {
    int stride = gridDim.x * blockDim.x;
    for (int i = blockIdx.x * blockDim.x + threadIdx.x; i < n4; i += stride) {
        float4 v = x[i];
        ushort4 o;
        o.x = f2bf(v.x); o.y = f2bf(v.y); o.z = f2bf(v.z); o.w = f2bf(v.w);
        xb[i] = o;
    }
}

// ---------- scatter pass 1 ----------
__global__ void tag_kernel(const int* __restrict__ rows, const int* __restrict__ cols,
                           unsigned* __restrict__ tag, int nnz) {
    int i = blockIdx.x * blockDim.x + threadIdx.x;
    if (i < nnz) {
        size_t loc = (size_t)cols[i] * IN_D + rows[i];
        atomicMax(&tag[loc], (unsigned)(i + 1));
    }
}

// ---------- scatter pass 2 ----------
__global__ void scat_kernel(const int* __restrict__ rows, const int* __restrict__ cols,
                            const float* __restrict__ w, const unsigned* __restrict__ tag,
                            unsigned short* __restrict__ Wt, int nnz) {
    int i = blockIdx.x * blockDim.x + threadIdx.x;
    if (i < nnz) {
        size_t loc = (size_t)cols[i] * IN_D + rows[i];
        if (tag[loc] == (unsigned)(i + 1)) Wt[loc] = f2bf(w[i]);
    }
}

// ---------- GEMM: 256x256 tile, BK=64, 8 waves, 8-phase schedule ----------
#define BM 256
#define BN 256
#define BK 64
#define NT (IN_D / BK)   // 64 K-tiles

#define QUAD(MI0, NI0) \
    _Pragma("unroll") \
    for (int mi = 0; mi < 4; ++mi) { \
      _Pragma("unroll") \
      for (int ni = 0; ni < 2; ++ni) { \
        _Pragma("unroll") \
        for (int ks = 0; ks < 2; ++ks) { \
          acc[(MI0)+mi][(NI0)+ni] = __builtin_amdgcn_mfma_f32_16x16x32_bf16( \
              a[mi][ks], b[ni][ks], acc[(MI0)+mi][(NI0)+ni], 0, 0, 0); \
        } } }

#define PHASE_TAIL(QUADCALL) \
    __builtin_amdgcn_s_barrier(); \
    asm volatile("s_waitcnt lgkmcnt(0)" ::: "memory"); \
    __builtin_amdgcn_sched_barrier(0); \
    __builtin_amdgcn_s_setprio(1); \
    QUADCALL; \
    __builtin_amdgcn_s_setprio(0); \
    __builtin_amdgcn_s_barrier();

__global__ __launch_bounds__(512) void gemm_kernel(
        const unsigned short* __restrict__ Xb,   // [BATCH][IN_D] bf16
        const unsigned short* __restrict__ Wt,   // [OUT_D][IN_D] bf16
        const float* __restrict__ bias,
        float* __restrict__ out)                 // [BATCH][OUT_D] fp32
{
    // [dbuf][side A=0/B=1][half][j*64 + k]   (128 KiB total)
    __shared__ unsigned short lds[2][2][2][128 * 64];

    const int tid  = threadIdx.x;
    const int lane = tid & 63;
    const int wave = tid >> 6;
    const int m0 = blockIdx.y * BM;
    const int n0 = blockIdx.x * BN;
    const int wm = (wave >> 2) * 128;
    const int wn = (wave & 3) * 64;

    const int lr = lane & 15;
    const int kg = lane >> 4;
    const int x7 = lr & 7;
    const int l8 = lane >> 3;      // staging: row within 8-row chunk
    const int c8 = lane & 7;       // staging: 16B slot within 128B row

    // swizzled physical k-elem offsets for fragment reads (ks = 0/1)
    const int kp0 = ((0 * 4 + kg) ^ x7) * 8;
    const int kp1 = ((1 * 4 + kg) ^ x7) * 8;

    // A-frag LDS row index base: j = (wave>>2)*64 + (mi&3)*16 + lr
    const int jA_base = (wave >> 2) * 64 + lr;
    // B-frag LDS row index per ni
    int jB[4];
    #pragma unroll
    for (int ni = 0; ni < 4; ++ni) {
        int r16 = wn + ni * 16;
        jB[ni] = (r16 & 31) + ((r16 >> 6) << 5) + lr;
    }

    // stage one half-tile (2 x gload_lds per wave); LDS dest linear, global src
    // inverse-swizzled: lane content k-elem = 8*(c8 ^ (j&7)), j&7 == l8
    auto stageA = [&](int d, int h, int kt) {
        #pragma unroll
        for (int s = 0; s < 2; ++s) {
            int j = wave * 16 + s * 8 + l8;
            int trow = (j & 63) + h * 64 + ((j >> 6) << 7);
            const unsigned short* src =
                Xb + (size_t)(m0 + trow) * IN_D + kt * BK + 8 * (c8 ^ l8);
            gload_lds16(src, &lds[d][0][h][(wave * 16 + s * 8) * 64]);
        }
    };
    auto stageB = [&](int d, int h, int kt) {
        #pragma unroll
        for (int s = 0; s < 2; ++s) {
            int j = wave * 16 + s * 8 + l8;
            int trow = (j & 31) + h * 32 + ((j >> 5) << 6);
            const unsigned short* src =
                Wt + (size_t)(n0 + trow) * IN_D + kt * BK + 8 * (c8 ^ l8);
            gload_lds16(src, &lds[d][1][h][(wave * 16 + s * 8) * 64]);
        }
    };

    f32x4 acc[8][4] = {};
    short8 a[4][2], b[2][2];

    // ---- prologue: tile0 (all 4 halves) -> buf0; tile1 {A-h0,B-h1,A-h1} -> buf1
    stageA(0, 0, 0); stageB(0, 0, 0); stageB(0, 1, 0); stageA(0, 1, 0);
    stageA(1, 0, 1); stageB(1, 1, 1); stageA(1, 1, 1);
    asm volatile("s_waitcnt vmcnt(6)" ::: "memory");
    __builtin_amdgcn_s_barrier();

    for (int t = 0; t < NT; ++t) {
        const int cur = t & 1, nxt = cur ^ 1;
        const int kt1 = (t + 1) & (NT - 1);
        const int kt2 = (t + 2) & (NT - 1);

        // ---- P1: read A-h0(8) + B-h0(4); stage B-h0(t+1) -> nxt
        #pragma unroll
        for (int mi = 0; mi < 4; ++mi) {
            a[mi][0] = *(const short8*)&lds[cur][0][0][(jA_base + mi * 16) * 64 + kp0];
            a[mi][1] = *(const short8*)&lds[cur][0][0][(jA_base + mi * 16) * 64 + kp1];
        }
        b[0][0] = *(const short8*)&lds[cur][1][0][jB[0] * 64 + kp0];
        b[0][1] = *(const short8*)&lds[cur][1][0][jB[0] * 64 + kp1];
        b[1][0] = *(const short8*)&lds[cur][1][0][jB[1] * 64 + kp0];
        b[1][1] = *(const short8*)&lds[cur][1][0][jB[1] * 64 + kp1];
        stageB(nxt, 0, kt1);
        PHASE_TAIL(QUAD(0, 0))

        // ---- P2: read B-h1(4); stage A-h0(t+2) -> cur
        b[0][0] = *(const short8*)&lds[cur][1][1][jB[2] * 64 + kp0];
        b[0][1] = *(const short8*)&lds[cur][1][1][jB[2] * 64 + kp1];
        b[1][0] = *(const short8*)&lds[cur][1][1][jB[3] * 64 + kp0];
        b[1][1] = *(const short8*)&lds[cur][1][1][jB[3] * 64 + kp1];
        stageA(cur, 0, kt2);
        PHASE_TAIL(QUAD(0, 2))

        // ---- P3: read A-h1(8); stage B-h1(t+2) -> cur
        #pragma unroll
        for (int mi = 0; mi < 4; ++mi) {
            a[mi][0] = *(const short8*)&lds[cur][0][1][(jA_base + mi * 16) * 64 + kp0];
            a[mi][1] = *(const short8*)&lds[cur][0][1][(jA_base + mi * 16) * 64 + kp1];
        }
        stageB(cur, 1, kt2);
        PHASE_TAIL(QUAD(4, 2))

        // ---- P4: re-read B-h0(4); stage A-h1(t+2) -> cur; counted vmcnt
        b[0][0] = *(const short8*)&lds[cur][1][0][jB[0] * 64 + kp0];
        b[0][1] = *(const short8*)&lds[cur][1][0][jB[0] * 64 + kp1];
        b[1][0] = *(const short8*)&lds[cur][1][0][jB[1] * 64 + kp0];
        b[1][1] = *(const short8*)&lds[cur][1][0][jB[1] * 64 + kp1];
        stageA(cur, 1, kt2);
        asm volatile("s_waitcnt vmcnt(6)" ::: "memory");  // tile t+1 fully landed
        PHASE_TAIL(QUAD(4, 0))
    }

    // ---- epilogue: bias + leaky_relu, fp32 store
    float bfrag[4];
    #pragma unroll
    for (int ni = 0; ni < 4; ++ni) bfrag[ni] = bias[n0 + wn + ni * 16 + lr];

    #pragma unroll
    for (int mi = 0; mi < 8; ++mi) {
        #pragma unroll
        for (int ni = 0; ni < 4; ++ni) {
            const int col = n0 + wn + ni * 16 + lr;
            #pragma unroll
            for (int r = 0; r < 4; ++r) {
                const int row = m0 + wm + mi * 16 + kg * 4 + r;
                float v = acc[mi][ni][r] + bfrag[ni];
                v = v > 0.0f ? v : v * NEG_SLOPE;
                out[(size_t)row * OUT_D + col] = v;
            }
        }
    }
}

// ---------- launch ----------
extern "C" void kernel_launch(void* const* d_in, const int* in_sizes, int n_in,
                              void* d_out, int out_size, void* d_ws, size_t ws_size,
                              hipStream_t stream) {
    const float* x    = (const float*)d_in[0];
    const float* w    = (const float*)d_in[1];
    const float* bias = (const float*)d_in[2];
    const int*   rows = (const int*)d_in[3];
    const int*   cols = (const int*)d_in[4];
    const int nnz = in_sizes[1];
    float* out = (float*)d_out;

    const size_t NW = (size_t)IN_D * OUT_D;
    unsigned*        tag = (unsigned*)d_ws;
    unsigned short*  Wt  = (unsigned short*)((char*)d_ws + NW * 4);
    unsigned short*  Xb  = (unsigned short*)((char*)d_ws + NW * 4 + NW * 2);

    zero_kernel<<<2048, 256, 0, stream>>>((uint4*)d_ws, (int)((NW * 6) / 16));
    cvt_kernel<<<2048, 256, 0, stream>>>((const float4*)x, (ushort4*)Xb,
                                         (int)((size_t)BATCH * IN_D / 4));
    tag_kernel<<<(nnz + 255) / 256, 256, 0, stream>>>(rows, cols, tag, nnz);
    scat_kernel<<<(nnz + 255) / 256, 256, 0, stream>>>(rows, cols, w, tag, Wt, nnz);

    dim3 grid(OUT_D / BN, BATCH / BM);
    gemm_kernel<<<grid, 512, 0, stream>>>(Xb, Wt, bias, out);
}

// Round 4
// 269.868 us; speedup vs baseline: 1.3639x; 1.0227x over previous
//
#include <hip/hip_runtime.h>
#include <stdint.h>

#define IN_D  4096
#define OUT_D 4096
#define BATCH 4096
#define NEG_SLOPE 0.1f

typedef __attribute__((ext_vector_type(8))) short short8;
typedef __attribute__((ext_vector_type(4))) float f32x4;

// ---------- helpers ----------
__device__ __forceinline__ unsigned short f2bf(float f) {
    unsigned u = __builtin_bit_cast(unsigned, f);
    u += 0x7FFFu + ((u >> 16) & 1u);
    return (unsigned short)(u >> 16);
}

__device__ __forceinline__ void gload_lds16(const unsigned short* gsrc, unsigned short* ldsp) {
    __builtin_amdgcn_global_load_lds(
        (const __attribute__((address_space(1))) unsigned int*)gsrc,
        (__attribute__((address_space(3))) unsigned int*)ldsp,
        16, 0, 0);
}

// ---------- prep1: zero tag+Wt (96 MiB) AND cvt x->bf16, fused ----------
__global__ void prep1_kernel(const float4* __restrict__ x, ushort4* __restrict__ xb,
                             uint4* __restrict__ z, int nz4, int nx4) {
    const int stride = gridDim.x * blockDim.x;
    const int i0 = blockIdx.x * blockDim.x + threadIdx.x;
    uint4 zz = make_uint4(0u, 0u, 0u, 0u);
    for (int i = i0; i < nz4; i += stride) z[i] = zz;
    for (int i = i0; i < nx4; i += stride) {
        float4 v = x[i];
        ushort4 o;
        o.x = f2bf(v.x); o.y = f2bf(v.y); o.z = f2bf(v.z); o.w = f2bf(v.w);
        xb[i] = o;
    }
}

// ---------- scatter pass 1: last-write-wins tag ----------
__global__ void tag_kernel(const int* __restrict__ rows, const int* __restrict__ cols,
                           unsigned* __restrict__ tag, int nnz) {
    int i = blockIdx.x * blockDim.x + threadIdx.x;
    if (i < nnz) {
        size_t loc = (size_t)cols[i] * IN_D + rows[i];
        atomicMax(&tag[loc], (unsigned)(i + 1));
    }
}

// ---------- scatter pass 2: winner writes bf16 weight ----------
__global__ void scat_kernel(const int* __restrict__ rows, const int* __restrict__ cols,
                            const float* __restrict__ w, const unsigned* __restrict__ tag,
                            unsigned short* __restrict__ Wt, int nnz) {
    int i = blockIdx.x * blockDim.x + threadIdx.x;
    if (i < nnz) {
        size_t loc = (size_t)cols[i] * IN_D + rows[i];
        if (tag[loc] == (unsigned)(i + 1)) Wt[loc] = f2bf(w[i]);
    }
}

// ---------- GEMM: 256x256 tile, BK=64, 8 waves, 4-phase/K-tile schedule ----------
#define BM 256
#define BN 256
#define BK 64
#define NT (IN_D / BK)   // 64 K-tiles

#define QUAD(MI0, NI0, BREG) \
    _Pragma("unroll") \
    for (int mi = 0; mi < 4; ++mi) { \
      _Pragma("unroll") \
      for (int ni = 0; ni < 2; ++ni) { \
        _Pragma("unroll") \
        for (int ks = 0; ks < 2; ++ks) { \
          acc[(MI0)+mi][(NI0)+ni] = __builtin_amdgcn_mfma_f32_16x16x32_bf16( \
              a[mi][ks], BREG[ni][ks], acc[(MI0)+mi][(NI0)+ni], 0, 0, 0); \
        } } }

#define PHASE_TAIL(QUADCALL) \
    __builtin_amdgcn_s_barrier(); \
    asm volatile("s_waitcnt lgkmcnt(0)" ::: "memory"); \
    __builtin_amdgcn_sched_barrier(0); \
    __builtin_amdgcn_s_setprio(1); \
    QUADCALL; \
    __builtin_amdgcn_s_setprio(0); \
    __builtin_amdgcn_s_barrier();

__global__ __launch_bounds__(512) void gemm_kernel(
        const unsigned short* __restrict__ Xb,   // [BATCH][IN_D] bf16
        const unsigned short* __restrict__ Wt,   // [OUT_D][IN_D] bf16
        const float* __restrict__ bias,
        float* __restrict__ out)                 // [BATCH][OUT_D] fp32
{
    // [dbuf][side A=0/B=1][half][j*64 + k]   (128 KiB)
    __shared__ unsigned short lds[2][2][2][128 * 64];

    const int tid  = threadIdx.x;
    const int lane = tid & 63;
    const int wave = tid >> 6;

    // bijective XCD swizzle (nwg=256, 8 XCDs, 256%8==0)
    const int lin = blockIdx.y * 16 + blockIdx.x;
    const int swz = (lin & 7) * 32 + (lin >> 3);
    const int m0 = (swz >> 4) * BM;
    const int n0 = (swz & 15) * BN;

    const int wm = (wave >> 2) * 128;
    const int wn = (wave & 3) * 64;

    const int lr = lane & 15;
    const int kg = lane >> 4;
    const int x7 = lr & 7;
    const int l8 = lane >> 3;
    const int c8 = lane & 7;

    // swizzled physical k-elem offsets (bank-conflict-free reads; verified 0 conflicts)
    const int kp0 = ((0 * 4 + kg) ^ x7) * 8;
    const int kp1 = ((1 * 4 + kg) ^ x7) * 8;

    const int jA_base = (wave >> 2) * 64 + lr;
    int jB[4];
    #pragma unroll
    for (int ni = 0; ni < 4; ++ni) {
        int r16 = wn + ni * 16;
        jB[ni] = (r16 & 31) + ((r16 >> 6) << 5) + lr;
    }

    auto stageA = [&](int d, int h, int kt) {
        #pragma unroll
        for (int s = 0; s < 2; ++s) {
            int j = wave * 16 + s * 8 + l8;
            int trow = (j & 63) + h * 64 + ((j >> 6) << 7);
            const unsigned short* src =
                Xb + (size_t)(m0 + trow) * IN_D + kt * BK + 8 * (c8 ^ l8);
            gload_lds16(src, &lds[d][0][h][(wave * 16 + s * 8) * 64]);
        }
    };
    auto stageB = [&](int d, int h, int kt) {
        #pragma unroll
        for (int s = 0; s < 2; ++s) {
            int j = wave * 16 + s * 8 + l8;
            int trow = (j & 31) + h * 32 + ((j >> 5) << 6);
            const unsigned short* src =
                Wt + (size_t)(n0 + trow) * IN_D + kt * BK + 8 * (c8 ^ l8);
            gload_lds16(src, &lds[d][1][h][(wave * 16 + s * 8) * 64]);
        }
    };

    f32x4 acc[8][4] = {};
    short8 a[4][2], b0[2][2], b1[2][2];

    // prologue: tile0 all halves -> buf0; tile1 {A-h0,B-h1,A-h1} -> buf1
    stageA(0, 0, 0); stageB(0, 0, 0); stageB(0, 1, 0); stageA(0, 1, 0);
    stageA(1, 0, 1); stageB(1, 1, 1); stageA(1, 1, 1);
    asm volatile("s_waitcnt vmcnt(6)" ::: "memory");
    __builtin_amdgcn_s_barrier();

    for (int t = 0; t < NT; ++t) {
        const int cur = t & 1, nxt = cur ^ 1;
        const int kt1 = (t + 1) & (NT - 1);
        const int kt2 = (t + 2) & (NT - 1);

        // P1: read A-h0(8) + B-h0(4 -> b0); stage B-h0(t+1) -> nxt
        #pragma unroll
        for (int mi = 0; mi < 4; ++mi) {
            a[mi][0] = *(const short8*)&lds[cur][0][0][(jA_base + mi * 16) * 64 + kp0];
            a[mi][1] = *(const short8*)&lds[cur][0][0][(jA_base + mi * 16) * 64 + kp1];
        }
        b0[0][0] = *(const short8*)&lds[cur][1][0][jB[0] * 64 + kp0];
        b0[0][1] = *(const short8*)&lds[cur][1][0][jB[0] * 64 + kp1];
        b0[1][0] = *(const short8*)&lds[cur][1][0][jB[1] * 64 + kp0];
        b0[1][1] = *(const short8*)&lds[cur][1][0][jB[1] * 64 + kp1];
        stageB(nxt, 0, kt1);
        PHASE_TAIL(QUAD(0, 0, b0))

        // P2: read B-h1(4 -> b1); stage A-h0(t+2) -> cur
        b1[0][0] = *(const short8*)&lds[cur][1][1][jB[2] * 64 + kp0];
        b1[0][1] = *(const short8*)&lds[cur][1][1][jB[2] * 64 + kp1];
        b1[1][0] = *(const short8*)&lds[cur][1][1][jB[3] * 64 + kp0];
        b1[1][1] = *(const short8*)&lds[cur][1][1][jB[3] * 64 + kp1];
        stageA(cur, 0, kt2);
        PHASE_TAIL(QUAD(0, 2, b1))

        // P3: read A-h1(8); stage B-h1(t+2) -> cur  (b1 reused from regs)
        #pragma unroll
        for (int mi = 0; mi < 4; ++mi) {
            a[mi][0] = *(const short8*)&lds[cur][0][1][(jA_base + mi * 16) * 64 + kp0];
            a[mi][1] = *(const short8*)&lds[cur][0][1][(jA_base + mi * 16) * 64 + kp1];
        }
        stageB(cur, 1, kt2);
        PHASE_TAIL(QUAD(4, 2, b1))

        // P4: no ds_reads (b0 reused from regs); stage A-h1(t+2) -> cur; counted vmcnt
        stageA(cur, 1, kt2);
        asm volatile("s_waitcnt vmcnt(6)" ::: "memory");  // tile t+1 fully landed
        PHASE_TAIL(QUAD(4, 0, b0))
    }

    // epilogue: bias + leaky_relu, fp32 store
    float bfrag[4];
    #pragma unroll
    for (int ni = 0; ni < 4; ++ni) bfrag[ni] = bias[n0 + wn + ni * 16 + lr];

    #pragma unroll
    for (int mi = 0; mi < 8; ++mi) {
        #pragma unroll
        for (int ni = 0; ni < 4; ++ni) {
            const int col = n0 + wn + ni * 16 + lr;
            #pragma unroll
            for (int r = 0; r < 4; ++r) {
                const int row = m0 + wm + mi * 16 + kg * 4 + r;
                float v = acc[mi][ni][r] + bfrag[ni];
                v = v > 0.0f ? v : v * NEG_SLOPE;
                out[(size_t)row * OUT_D + col] = v;
            }
        }
    }
}

// ---------- launch ----------
extern "C" void kernel_launch(void* const* d_in, const int* in_sizes, int n_in,
                              void* d_out, int out_size, void* d_ws, size_t ws_size,
                              hipStream_t stream) {
    const float* x    = (const float*)d_in[0];
    const float* w    = (const float*)d_in[1];
    const float* bias = (const float*)d_in[2];
    const int*   rows = (const int*)d_in[3];
    const int*   cols = (const int*)d_in[4];
    const int nnz = in_sizes[1];
    float* out = (float*)d_out;

    const size_t NW = (size_t)IN_D * OUT_D;
    unsigned*        tag = (unsigned*)d_ws;
    unsigned short*  Wt  = (unsigned short*)((char*)d_ws + NW * 4);
    unsigned short*  Xb  = (unsigned short*)((char*)d_ws + NW * 4 + NW * 2);

    prep1_kernel<<<4096, 256, 0, stream>>>((const float4*)x, (ushort4*)Xb, (uint4*)d_ws,
                                           (int)((NW * 6) / 16),
                                           (int)((size_t)BATCH * IN_D / 4));
    tag_kernel<<<(nnz + 255) / 256, 256, 0, stream>>>(rows, cols, tag, nnz);
    scat_kernel<<<(nnz + 255) / 256, 256, 0, stream>>>(rows, cols, w, tag, Wt, nnz);

    dim3 grid(OUT_D / BN, BATCH / BM);
    gemm_kernel<<<grid, 512, 0, stream>>>(Xb, Wt, bias, out);
}

// Round 5
// 228.765 us; speedup vs baseline: 1.6089x; 1.1797x over previous
//
#include <hip/hip_runtime.h>
#include <stdint.h>

#define IN_D  4096
#define OUT_D 4096
#define BATCH 4096
#define NEG_SLOPE 0.1f

typedef __attribute__((ext_vector_type(8))) short short8;
typedef __attribute__((ext_vector_type(4))) float f32x4;

// ---------- helpers ----------
__device__ __forceinline__ unsigned short f2bf(float f) {
    unsigned u = __builtin_bit_cast(unsigned, f);
    u += 0x7FFFu + ((u >> 16) & 1u);
    return (unsigned short)(u >> 16);
}

__device__ __forceinline__ void gload_lds16(const unsigned short* gsrc, unsigned short* ldsp) {
    __builtin_amdgcn_global_load_lds(
        (const __attribute__((address_space(1))) unsigned int*)gsrc,
        (__attribute__((address_space(3))) unsigned int*)ldsp,
        16, 0, 0);
}

// ---------- prep A: zero tag (64 MiB) ----------
__global__ void zerotag_kernel(uint4* __restrict__ p, int n4) {
    const int stride = gridDim.x * blockDim.x;
    uint4 z = make_uint4(0u, 0u, 0u, 0u);
    for (int i = blockIdx.x * blockDim.x + threadIdx.x; i < n4; i += stride) p[i] = z;
}

// ---------- prep B: last-write-wins tag atomics FUSED with x->bf16 cvt ----------
__global__ void tagcvt_kernel(const int* __restrict__ rows, const int* __restrict__ cols,
                              unsigned* __restrict__ tag, int nnz,
                              const float4* __restrict__ x, ushort4* __restrict__ xb, int nx4) {
    const int stride = gridDim.x * blockDim.x;
    const int i0 = blockIdx.x * blockDim.x + threadIdx.x;
    // atomics first: fire-and-forget, pipeline under the cvt streaming below
    for (int i = i0; i < nnz; i += stride) {
        size_t loc = (size_t)cols[i] * IN_D + rows[i];   // Wt[col][row]
        atomicMax(&tag[loc], (unsigned)(i + 1));
    }
    for (int i = i0; i < nx4; i += stride) {
        float4 v = x[i];
        ushort4 o;
        o.x = f2bf(v.x); o.y = f2bf(v.y); o.z = f2bf(v.z); o.w = f2bf(v.w);
        xb[i] = o;
    }
}

// ---------- prep C: dense scan — Wt[loc] = tag ? bf16(w[tag-1]) : 0 ----------
// Streaming read of tag (64 MiB) + gathers from w (6.7 MB, L2/L3-resident) +
// dense coalesced write of ALL of Wt (32 MiB) — replaces random scat + Wt zero.
__global__ void densescat_kernel(const uint4* __restrict__ tag4,
                                 const float* __restrict__ w,
                                 ushort4* __restrict__ Wt4, int n4) {
    const int stride = gridDim.x * blockDim.x;
    for (int i = blockIdx.x * blockDim.x + threadIdx.x; i < n4; i += stride) {
        uint4 t = tag4[i];
        ushort4 o;
        o.x = t.x ? f2bf(w[t.x - 1]) : (unsigned short)0;
        o.y = t.y ? f2bf(w[t.y - 1]) : (unsigned short)0;
        o.z = t.z ? f2bf(w[t.z - 1]) : (unsigned short)0;
        o.w = t.w ? f2bf(w[t.w - 1]) : (unsigned short)0;
        Wt4[i] = o;
    }
}

// ---------- GEMM: 256x256 tile, BK=64, 8 waves, 4-phase/K-tile schedule ----------
#define BM 256
#define BN 256
#define BK 64
#define NT (IN_D / BK)   // 64 K-tiles

#define QUAD(MI0, NI0, BREG) \
    _Pragma("unroll") \
    for (int mi = 0; mi < 4; ++mi) { \
      _Pragma("unroll") \
      for (int ni = 0; ni < 2; ++ni) { \
        _Pragma("unroll") \
        for (int ks = 0; ks < 2; ++ks) { \
          acc[(MI0)+mi][(NI0)+ni] = __builtin_amdgcn_mfma_f32_16x16x32_bf16( \
              a[mi][ks], BREG[ni][ks], acc[(MI0)+mi][(NI0)+ni], 0, 0, 0); \
        } } }

#define PHASE_TAIL(QUADCALL) \
    __builtin_amdgcn_s_barrier(); \
    asm volatile("s_waitcnt lgkmcnt(0)" ::: "memory"); \
    __builtin_amdgcn_sched_barrier(0); \
    __builtin_amdgcn_s_setprio(1); \
    QUADCALL; \
    __builtin_amdgcn_s_setprio(0); \
    __builtin_amdgcn_s_barrier();

__global__ __launch_bounds__(512) void gemm_kernel(
        const unsigned short* __restrict__ Xb,   // [BATCH][IN_D] bf16
        const unsigned short* __restrict__ Wt,   // [OUT_D][IN_D] bf16
        const float* __restrict__ bias,
        float* __restrict__ out)                 // [BATCH][OUT_D] fp32
{
    // [dbuf][side A=0/B=1][half][j*64 + k]   (128 KiB)
    __shared__ unsigned short lds[2][2][2][128 * 64];

    const int tid  = threadIdx.x;
    const int lane = tid & 63;
    const int wave = tid >> 6;

    // bijective XCD swizzle (nwg=256, 8 XCDs, 256%8==0)
    const int lin = blockIdx.y * 16 + blockIdx.x;
    const int swz = (lin & 7) * 32 + (lin >> 3);
    const int m0 = (swz >> 4) * BM;
    const int n0 = (swz & 15) * BN;

    const int wm = (wave >> 2) * 128;
    const int wn = (wave & 3) * 64;

    const int lr = lane & 15;
    const int kg = lane >> 4;
    const int x7 = lr & 7;
    const int l8 = lane >> 3;
    const int c8 = lane & 7;

    // swizzled physical k-elem offsets (bank-conflict-free; measured 0 conflicts)
    const int kp0 = ((0 * 4 + kg) ^ x7) * 8;
    const int kp1 = ((1 * 4 + kg) ^ x7) * 8;

    const int jA_base = (wave >> 2) * 64 + lr;
    int jB[4];
    #pragma unroll
    for (int ni = 0; ni < 4; ++ni) {
        int r16 = wn + ni * 16;
        jB[ni] = (r16 & 31) + ((r16 >> 6) << 5) + lr;
    }

    auto stageA = [&](int d, int h, int kt) {
        #pragma unroll
        for (int s = 0; s < 2; ++s) {
            int j = wave * 16 + s * 8 + l8;
            int trow = (j & 63) + h * 64 + ((j >> 6) << 7);
            const unsigned short* src =
                Xb + (size_t)(m0 + trow) * IN_D + kt * BK + 8 * (c8 ^ l8);
            gload_lds16(src, &lds[d][0][h][(wave * 16 + s * 8) * 64]);
        }
    };
    auto stageB = [&](int d, int h, int kt) {
        #pragma unroll
        for (int s = 0; s < 2; ++s) {
            int j = wave * 16 + s * 8 + l8;
            int trow = (j & 31) + h * 32 + ((j >> 5) << 6);
            const unsigned short* src =
                Wt + (size_t)(n0 + trow) * IN_D + kt * BK + 8 * (c8 ^ l8);
            gload_lds16(src, &lds[d][1][h][(wave * 16 + s * 8) * 64]);
        }
    };

    f32x4 acc[8][4] = {};
    short8 a[4][2], b0[2][2], b1[2][2];

    // prologue: tile0 all halves -> buf0; tile1 {A-h0,B-h1,A-h1} -> buf1
    // (tile1 B-h0 staged by t=0's P1)
    stageA(0, 0, 0); stageB(0, 0, 0); stageB(0, 1, 0); stageA(0, 1, 0);
    stageA(1, 0, 1); stageB(1, 1, 1); stageA(1, 1, 1);
    asm volatile("s_waitcnt vmcnt(6)" ::: "memory");   // tile0 fully landed
    __builtin_amdgcn_s_barrier();
    // prefetch tile0 A-h0 + B-h0 into regs (P1 tail lgkmcnt covers completion)
    #pragma unroll
    for (int mi = 0; mi < 4; ++mi) {
        a[mi][0] = *(const short8*)&lds[0][0][0][(jA_base + mi * 16) * 64 + kp0];
        a[mi][1] = *(const short8*)&lds[0][0][0][(jA_base + mi * 16) * 64 + kp1];
    }
    b0[0][0] = *(const short8*)&lds[0][1][0][jB[0] * 64 + kp0];
    b0[0][1] = *(const short8*)&lds[0][1][0][jB[0] * 64 + kp1];
    b0[1][0] = *(const short8*)&lds[0][1][0][jB[1] * 64 + kp0];
    b0[1][1] = *(const short8*)&lds[0][1][0][jB[1] * 64 + kp1];

    for (int t = 0; t < NT; ++t) {
        const int cur = t & 1, nxt = cur ^ 1;
        const int kt1 = (t + 1) & (NT - 1);
        const int kt2 = (t + 2) & (NT - 1);

        // P1: no ds_reads (a/b0 prefetched); stage B-h0(t+1) -> nxt
        stageB(nxt, 0, kt1);
        PHASE_TAIL(QUAD(0, 0, b0))

        // P2: read B-h1(4 -> b1); stage A-h0(t+2) -> cur
        b1[0][0] = *(const short8*)&lds[cur][1][1][jB[2] * 64 + kp0];
        b1[0][1] = *(const short8*)&lds[cur][1][1][jB[2] * 64 + kp1];
        b1[1][0] = *(const short8*)&lds[cur][1][1][jB[3] * 64 + kp0];
        b1[1][1] = *(const short8*)&lds[cur][1][1][jB[3] * 64 + kp1];
        stageA(cur, 0, kt2);
        PHASE_TAIL(QUAD(0, 2, b1))

        // P3: read A-h1(8); stage B-h1(t+2) -> cur
        #pragma unroll
        for (int mi = 0; mi < 4; ++mi) {
            a[mi][0] = *(const short8*)&lds[cur][0][1][(jA_base + mi * 16) * 64 + kp0];
            a[mi][1] = *(const short8*)&lds[cur][0][1][(jA_base + mi * 16) * 64 + kp1];
        }
        stageB(cur, 1, kt2);
        PHASE_TAIL(QUAD(4, 2, b1))

        // P4: stage A-h1(t+2) -> cur; counted vmcnt; QUAD; then prefetch tile
        // t+1's A-h0/B-h0 from nxt (fully landed after vmcnt(6)+barrier) in the
        // MFMA shadow — consumed next iter P1.
        stageA(cur, 1, kt2);
        asm volatile("s_waitcnt vmcnt(6)" ::: "memory");  // tile t+1 fully landed
        __builtin_amdgcn_s_barrier();
        asm volatile("s_waitcnt lgkmcnt(0)" ::: "memory");
        __builtin_amdgcn_sched_barrier(0);
        __builtin_amdgcn_s_setprio(1);
        QUAD(4, 0, b0)
        __builtin_amdgcn_s_setprio(0);
        #pragma unroll
        for (int mi = 0; mi < 4; ++mi) {
            a[mi][0] = *(const short8*)&lds[nxt][0][0][(jA_base + mi * 16) * 64 + kp0];
            a[mi][1] = *(const short8*)&lds[nxt][0][0][(jA_base + mi * 16) * 64 + kp1];
        }
        b0[0][0] = *(const short8*)&lds[nxt][1][0][jB[0] * 64 + kp0];
        b0[0][1] = *(const short8*)&lds[nxt][1][0][jB[0] * 64 + kp1];
        b0[1][0] = *(const short8*)&lds[nxt][1][0][jB[1] * 64 + kp0];
        b0[1][1] = *(const short8*)&lds[nxt][1][0][jB[1] * 64 + kp1];
        __builtin_amdgcn_s_barrier();
    }

    // epilogue: bias + leaky_relu, fp32 store
    float bfrag[4];
    #pragma unroll
    for (int ni = 0; ni < 4; ++ni) bfrag[ni] = bias[n0 + wn + ni * 16 + lr];

    #pragma unroll
    for (int mi = 0; mi < 8; ++mi) {
        #pragma unroll
        for (int ni = 0; ni < 4; ++ni) {
            const int col = n0 + wn + ni * 16 + lr;
            #pragma unroll
            for (int r = 0; r < 4; ++r) {
                const int row = m0 + wm + mi * 16 + kg * 4 + r;
                float v = acc[mi][ni][r] + bfrag[ni];
                v = v > 0.0f ? v : v * NEG_SLOPE;
                out[(size_t)row * OUT_D + col] = v;
            }
        }
    }
}

// ---------- launch ----------
extern "C" void kernel_launch(void* const* d_in, const int* in_sizes, int n_in,
                              void* d_out, int out_size, void* d_ws, size_t ws_size,
                              hipStream_t stream) {
    const float* x    = (const float*)d_in[0];
    const float* w    = (const float*)d_in[1];
    const float* bias = (const float*)d_in[2];
    const int*   rows = (const int*)d_in[3];
    const int*   cols = (const int*)d_in[4];
    const int nnz = in_sizes[1];
    float* out = (float*)d_out;

    const size_t NW = (size_t)IN_D * OUT_D;
    unsigned*        tag = (unsigned*)d_ws;
    unsigned short*  Wt  = (unsigned short*)((char*)d_ws + NW * 4);
    unsigned short*  Xb  = (unsigned short*)((char*)d_ws + NW * 4 + NW * 2);

    // A: zero tag (64 MiB)
    zerotag_kernel<<<2048, 256, 0, stream>>>((uint4*)tag, (int)(NW / 4));
    // B: tag atomics + x->bf16 cvt fused
    tagcvt_kernel<<<2048, 256, 0, stream>>>(rows, cols, tag, nnz,
                                            (const float4*)x, (ushort4*)Xb,
                                            (int)((size_t)BATCH * IN_D / 4));
    // C: dense scan -> Wt (also zero-fills untouched locs)
    densescat_kernel<<<2048, 256, 0, stream>>>((const uint4*)tag, w,
                                               (ushort4*)Wt, (int)(NW / 4));

    dim3 grid(OUT_D / BN, BATCH / BM);
    gemm_kernel<<<grid, 512, 0, stream>>>(Xb, Wt, bias, out);
}